// Round 16
// baseline (355.196 us; speedup 1.0000x reference)
//
#include <hip/hip_runtime.h>

// DeltaModulationEncoder: x (16, 256, 8192) f32 -> spikes {-1,0,1} f32.
// Exact monolithic scan (recurrence serial per channel).
//
// Model (R12-R15 fit): per-step cost ~= 7 cyc x ninstr at 1 wave/SIMD, for
// code whose instrs depend on results 1-3 back. Ambiguous between (a) dep
// latency L~=7 with in-order issue and (b) ~7 cyc/instr solo-wave cadence.
// This round discriminates AND exploits (a): TWO channels per lane (A,B),
// instructions strictly alternated -> dep distance 2x, B issues in A's stall
// windows. (a) predicts ~37 cyc per PAIR of channel-steps -> ~130-150 us;
// (b) predicts null (~188 us).
//
// Structure: 128 blocks x 1 wave; lanes 0-15 active; channel A = blk*32+lane,
// B = A+16. Hand-asm memory pipeline (R12-proven): dual 8-deep dwordx4
// pipelines, dual rotating spike sets, exact counted s_waitcnt vmcnt(28)
// (= 4 vmem ops x 7 younger slots; loads land 8 slots (~1200 cyc) before
// use; stores never drained in-loop).
//
// Step = R13's 8-instr form verbatim (passed, absmax 0.0), B-renamed:
//   err = x - r; m = th - |err| (Sterbenz-exact, strict at ==th);
//   mask = m>>31; nth = mask & (sgn(err)|0.1f); r += nth (exactly the
//   reference's recon + net*th); spike = nth * 10.0f (exact {-1,0,1}).
// 10.0f hoisted to s11 so every step instr is 1 dword.
//
// Register map (fixed): v33 rA, v34 rB | v40 voffA, v41 voffB |
//   tempsA v46-v49, tempsB v51-v54 |
//   QA j: v[64+4j..67+4j], QB j: v[96+4j..99+4j]  (j=0..7)
//   PA j: v[128+4j..131+4j], PB j: v[160+4j..163+4j]
//   s8=+0.1f, s10=0x80000000, s11=10.0f.

constexpr int T    = 8192;
constexpr int NCH  = 4096;
constexpr int CPB  = 32;          // channels per block (16 lanes x 2 streams)
constexpr int NBLK = NCH / CPB;   // 128

// One interleaved element: step A (x=vXA -> spike vSA) alternated with
// step B (vXB -> vSB). Order keeps both chains' producers >=2 instrs back.
#define STEP2(XA,XB,SA,SB) \
  "v_sub_f32 v48, v" #XA ", v33\n\t"            /* A err  */ \
  "v_sub_f32 v53, v" #XB ", v34\n\t"            /* B err  */ \
  "v_sub_f32_e64 v46, s8, |v48|\n\t"            /* A m    */ \
  "v_and_b32 v47, s10, v48\n\t"                 /* A sgn  */ \
  "v_sub_f32_e64 v51, s8, |v53|\n\t"            /* B m    */ \
  "v_and_b32 v52, s10, v53\n\t"                 /* B sgn  */ \
  "v_ashrrev_i32 v46, 31, v46\n\t"              /* A mask */ \
  "v_or_b32 v49, s8, v47\n\t"                   /* A pm   */ \
  "v_ashrrev_i32 v51, 31, v51\n\t"              /* B mask */ \
  "v_or_b32 v54, s8, v52\n\t"                   /* B pm   */ \
  "v_and_b32 v49, v46, v49\n\t"                 /* A nth  */ \
  "v_and_b32 v54, v51, v54\n\t"                 /* B nth  */ \
  "v_add_f32 v33, v33, v49\n\t"                 /* A r+=  */ \
  "v_add_f32 v34, v34, v54\n\t"                 /* B r+=  */ \
  "v_mul_f32 v" #SA ", s11, v49\n\t"            /* A spk  */ \
  "v_mul_f32 v" #SB ", s11, v54\n\t"            /* B spk  */

#define CLOB \
  "memory","s8","s10","s11", \
  "v33","v34","v40","v41","v46","v47","v48","v49","v51","v52","v53","v54", \
  "v64","v65","v66","v67","v68","v69","v70","v71", \
  "v72","v73","v74","v75","v76","v77","v78","v79", \
  "v80","v81","v82","v83","v84","v85","v86","v87", \
  "v88","v89","v90","v91","v92","v93","v94","v95", \
  "v96","v97","v98","v99","v100","v101","v102","v103", \
  "v104","v105","v106","v107","v108","v109","v110","v111", \
  "v112","v113","v114","v115","v116","v117","v118","v119", \
  "v120","v121","v122","v123","v124","v125","v126","v127", \
  "v128","v129","v130","v131","v132","v133","v134","v135", \
  "v136","v137","v138","v139","v140","v141","v142","v143", \
  "v144","v145","v146","v147","v148","v149","v150","v151", \
  "v152","v153","v154","v155","v156","v157","v158","v159", \
  "v160","v161","v162","v163","v164","v165","v166","v167", \
  "v168","v169","v170","v171","v172","v173","v174","v175", \
  "v176","v177","v178","v179","v180","v181","v182","v183", \
  "v184","v185","v186","v187","v188","v189","v190","v191"

// Steady-state slot: exact wait + 4 interleaved elements + 2 stores + 2 loads
// (loads fetch chunk slot+8, consumed next iteration).
#define SLOT2(QA0,QA1,QA2,QA3, QB0,QB1,QB2,QB3, \
              PA0,PA1,PA2,PA3, PB0,PB1,PB2,PB3, OFFS,OFFL) asm volatile( \
  "s_waitcnt vmcnt(28)\n\t" \
  STEP2(QA0,QB0,PA0,PB0) STEP2(QA1,QB1,PA1,PB1) \
  STEP2(QA2,QB2,PA2,PB2) STEP2(QA3,QB3,PA3,PB3) \
  "global_store_dwordx4 v40, v[" #PA0 ":" #PA3 "], %1 offset:" #OFFS "\n\t" \
  "global_store_dwordx4 v41, v[" #PB0 ":" #PB3 "], %1 offset:" #OFFS "\n\t" \
  "global_load_dwordx4 v[" #QA0 ":" #QA3 "], v40, %0 offset:" #OFFL "\n\t" \
  "global_load_dwordx4 v[" #QB0 ":" #QB3 "], v41, %0 offset:" #OFFL "\n\t" \
  :: "s"(xp), "s"(op) : CLOB)

// Drain slot (after vmcnt(0)): no wait, no loads.
#define SLOTND2(QA0,QA1,QA2,QA3, QB0,QB1,QB2,QB3, \
                PA0,PA1,PA2,PA3, PB0,PB1,PB2,PB3, OFFS) asm volatile( \
  STEP2(QA0,QB0,PA0,PB0) STEP2(QA1,QB1,PA1,PB1) \
  STEP2(QA2,QB2,PA2,PB2) STEP2(QA3,QB3,PA3,PB3) \
  "global_store_dwordx4 v40, v[" #PA0 ":" #PA3 "], %1 offset:" #OFFS "\n\t" \
  "global_store_dwordx4 v41, v[" #PB0 ":" #PB3 "], %1 offset:" #OFFS "\n\t" \
  :: "s"(xp), "s"(op) : CLOB)

__global__ __launch_bounds__(64, 1) void dm_scan(const float* __restrict__ x,
                                                 float* __restrict__ out) {
    const int lane = threadIdx.x;
    if (lane >= 16) return;                   // lanes 16-63 exec-masked off
    const int chA = blockIdx.x * CPB + lane;  // stream A channel
    // stream B channel = chA + 16

    const float* xp = x;                      // uniform -> SGPR base
    float*       op = out;
    unsigned offA = (unsigned)chA * (unsigned)(T * 4);
    unsigned offB = offA + 16u * (unsigned)(T * 4);

    // Prologue: consts, recon=0, voffsets, fill both 8-slot pipelines, drain.
    asm volatile(
        "s_mov_b32 s8, 0x3dcccccd\n\t"        // +0.1f
        "s_mov_b32 s10, 0x80000000\n\t"       // sign mask
        "s_mov_b32 s11, 0x41200000\n\t"       // 10.0f
        "v_mov_b32 v33, 0\n\t"
        "v_mov_b32 v34, 0\n\t"
        "v_mov_b32 v40, %2\n\t"
        "v_mov_b32 v41, %3\n\t"
        "global_load_dwordx4 v[64:67],   v40, %0\n\t"
        "global_load_dwordx4 v[68:71],   v40, %0 offset:16\n\t"
        "global_load_dwordx4 v[72:75],   v40, %0 offset:32\n\t"
        "global_load_dwordx4 v[76:79],   v40, %0 offset:48\n\t"
        "global_load_dwordx4 v[80:83],   v40, %0 offset:64\n\t"
        "global_load_dwordx4 v[84:87],   v40, %0 offset:80\n\t"
        "global_load_dwordx4 v[88:91],   v40, %0 offset:96\n\t"
        "global_load_dwordx4 v[92:95],   v40, %0 offset:112\n\t"
        "global_load_dwordx4 v[96:99],   v41, %0\n\t"
        "global_load_dwordx4 v[100:103], v41, %0 offset:16\n\t"
        "global_load_dwordx4 v[104:107], v41, %0 offset:32\n\t"
        "global_load_dwordx4 v[108:111], v41, %0 offset:48\n\t"
        "global_load_dwordx4 v[112:115], v41, %0 offset:64\n\t"
        "global_load_dwordx4 v[116:119], v41, %0 offset:80\n\t"
        "global_load_dwordx4 v[120:123], v41, %0 offset:96\n\t"
        "global_load_dwordx4 v[124:127], v41, %0 offset:112\n\t"
        "s_waitcnt vmcnt(0)\n\t"
        :: "s"(xp), "s"(op), "v"(offA), "v"(offB)
        : CLOB);

    // 255 iterations x 8 slots; slot j consumes chunk (8it+j) of both
    // streams and prefetches chunk (8it+j+8). Last prefetch: it=254, j=7
    // -> chunk 2047 (in bounds).
#pragma clang loop unroll(disable)
    for (int it = 0; it < 255; ++it) {
        SLOT2( 64, 65, 66, 67,  96, 97, 98, 99, 128,129,130,131, 160,161,162,163,   0, 128);
        SLOT2( 68, 69, 70, 71, 100,101,102,103, 132,133,134,135, 164,165,166,167,  16, 144);
        SLOT2( 72, 73, 74, 75, 104,105,106,107, 136,137,138,139, 168,169,170,171,  32, 160);
        SLOT2( 76, 77, 78, 79, 108,109,110,111, 140,141,142,143, 172,173,174,175,  48, 176);
        SLOT2( 80, 81, 82, 83, 112,113,114,115, 144,145,146,147, 176,177,178,179,  64, 192);
        SLOT2( 84, 85, 86, 87, 116,117,118,119, 148,149,150,151, 180,181,182,183,  80, 208);
        SLOT2( 88, 89, 90, 91, 120,121,122,123, 152,153,154,155, 184,185,186,187,  96, 224);
        SLOT2( 92, 93, 94, 95, 124,125,126,127, 156,157,158,159, 188,189,190,191, 112, 240);
        asm volatile("v_add_u32 v40, 0x80, v40\n\t"
                     "v_add_u32 v41, 0x80, v41" ::: "v40","v41");
    }

    // Final 8 chunks (2040..2047): drain once, then compute+store only.
    asm volatile("s_waitcnt vmcnt(0)" ::: "memory");
    SLOTND2( 64, 65, 66, 67,  96, 97, 98, 99, 128,129,130,131, 160,161,162,163,   0);
    SLOTND2( 68, 69, 70, 71, 100,101,102,103, 132,133,134,135, 164,165,166,167,  16);
    SLOTND2( 72, 73, 74, 75, 104,105,106,107, 136,137,138,139, 168,169,170,171,  32);
    SLOTND2( 76, 77, 78, 79, 108,109,110,111, 140,141,142,143, 172,173,174,175,  48);
    SLOTND2( 80, 81, 82, 83, 112,113,114,115, 144,145,146,147, 176,177,178,179,  64);
    SLOTND2( 84, 85, 86, 87, 116,117,118,119, 148,149,150,151, 180,181,182,183,  80);
    SLOTND2( 88, 89, 90, 91, 120,121,122,123, 152,153,154,155, 184,185,186,187,  96);
    SLOTND2( 92, 93, 94, 95, 124,125,126,127, 156,157,158,159, 188,189,190,191, 112);
}

extern "C" void kernel_launch(void* const* d_in, const int* in_sizes, int n_in,
                              void* d_out, int out_size, void* d_ws, size_t ws_size,
                              hipStream_t stream) {
    const float* x   = (const float*)d_in[0];
    float*       out = (float*)d_out;
    dm_scan<<<NBLK, 64, 0, stream>>>(x, out);
}

// Round 17
// 150.327 us; speedup vs baseline: 2.3628x; 2.3628x over previous
//
#include <hip/hip_runtime.h>

// DeltaModulationEncoder: x (16, 256, 8192) f32 -> spikes {-1,0,1} f32.
// Exact monolithic scan (recurrence serial per channel).
//
// Calibrated model (fits R12-R16, all structures): wall = 8192 x ninstr x
// ~6.3 cyc at 1 wave/SIMD — pure per-wave issue cadence; dependencies and
// ILP irrelevant (R16's independent-chain interleave was a clean null at
// 6.0 cyc/instr). Memory fully hidden by the hand-asm 16-deep pipeline
// (R12+). Only lever: instructions per step.
//
// 6-instr step (was 8), bit-exact vs reference:
//   err   = x - r                      (identical sub)
//   u     = med3(err, -th, +th)        (clamp; +-th in VGPRs v30/v31)
//   w     = err - u                    (+0 inside deadband incl. ==th
//                                       boundary -> strict >, like ref;
//                                       outside: nonzero, sign(err),
//                                       |w| >= ulp(0.1) ~ 2^-27, Sterbenz)
//   s     = w * 2^127                  (|s| >= 2^100 or +-inf or +0)
//   spike = med3(s, -1.0, 1.0)         (exact {-1,0,+1}, direct to store reg)
//   r     = fma(spike, th, r)          (spike*th EXACT +-0.1f/+0 -> fma ==
//                                       ref's mul+add bit-identically;
//                                       r never -0.0f so +0 case keeps r)
// NaN impossible (finite inputs).
//
// Register map (fixed): v33 recon | v40 voffset | v48,v49 temps |
//   v30=-0.1f v31=+0.1f | s8=+0.1f s11=2^127 |
//   v[64+4j..67+4j]   q[j] 16-deep load pipeline (j=0..15)
//   v[128+4j..131+4j] spike set j (rotating; store-source regs overwritten
//                     only after vmcnt proves the store retired)
// Per slot: s_waitcnt vmcnt(30) [exact: my load and this spike-set's
// previous store are both 31+ ops old], 4 steps, store(chunk),
// load(chunk+16). 256 blocks x 1 wave; lanes 0-15 own one channel each.

constexpr int T    = 8192;
constexpr int NCH  = 4096;
constexpr int CPB  = 16;
constexpr int NBLK = NCH / CPB;   // 256

#define STEP(X,S) \
  "v_sub_f32 v48, v" #X ", v33\n\t"            /* err = x - r          */ \
  "v_med3_f32 v49, v48, v30, v31\n\t"          /* u = clamp(err,-th,th)*/ \
  "v_sub_f32 v48, v48, v49\n\t"                /* w = err - u          */ \
  "v_mul_f32 v49, s11, v48\n\t"                /* s = w * 2^127        */ \
  "v_med3_f32 v" #S ", v49, -1.0, 1.0\n\t"     /* spike in {-1,0,1}    */ \
  "v_fma_f32 v33, v" #S ", s8, v33\n\t"        /* r += spike*th (exact)*/

#define SLOT_CLOB(Q0,Q1,Q2,Q3,P0,P1,P2,P3) \
  "memory","s8","s11","v30","v31","v33","v48","v49", \
  "v" #Q0,"v" #Q1,"v" #Q2,"v" #Q3,"v" #P0,"v" #P1,"v" #P2,"v" #P3

// Steady-state slot: wait(exact) + 4 steps + store(chunk) + load(chunk+16).
#define SLOT(Q0,Q1,Q2,Q3,P0,P1,P2,P3,OFFS,OFFL) asm volatile( \
  "s_waitcnt vmcnt(30)\n\t" \
  STEP(Q0,P0) STEP(Q1,P1) STEP(Q2,P2) STEP(Q3,P3) \
  "global_store_dwordx4 v40, v[" #P0 ":" #P3 "], %1 offset:" #OFFS "\n\t" \
  "global_load_dwordx4 v[" #Q0 ":" #Q3 "], v40, %0 offset:" #OFFL "\n\t" \
  :: "s"(xp), "s"(op) : SLOT_CLOB(Q0,Q1,Q2,Q3,P0,P1,P2,P3))

// Final-iteration slot: everything drained beforehand; no wait, no load.
#define SLOTND(Q0,Q1,Q2,Q3,P0,P1,P2,P3,OFFS) asm volatile( \
  STEP(Q0,P0) STEP(Q1,P1) STEP(Q2,P2) STEP(Q3,P3) \
  "global_store_dwordx4 v40, v[" #P0 ":" #P3 "], %1 offset:" #OFFS "\n\t" \
  :: "s"(xp), "s"(op) : SLOT_CLOB(Q0,Q1,Q2,Q3,P0,P1,P2,P3))

__global__ __launch_bounds__(64, 1) void dm_scan(const float* __restrict__ x,
                                                 float* __restrict__ out) {
    const int lane = threadIdx.x;
    if (lane >= CPB) return;                  // exec = 0xFFFF for the rest
    const int ch = blockIdx.x * CPB + lane;

    const float* xp = x;                      // uniform -> "s" (SADDR base)
    float*       op = out;
    unsigned off0 = (unsigned)ch * (unsigned)(T * 4);   // per-lane byte offset

    // Prologue: consts, recon=0, voffset, fill the 16-slot pipeline, drain.
    asm volatile(
        "s_mov_b32 s8, 0x3dcccccd\n\t"        // +0.1f (fma operand)
        "s_mov_b32 s11, 0x7e800000\n\t"       // 2^127
        "v_mov_b32 v30, 0xbdcccccd\n\t"       // -0.1f (med3 bound)
        "v_mov_b32 v31, 0x3dcccccd\n\t"       // +0.1f (med3 bound)
        "v_mov_b32 v33, 0\n\t"
        "v_mov_b32 v40, %2\n\t"
        "global_load_dwordx4 v[64:67],   v40, %0\n\t"
        "global_load_dwordx4 v[68:71],   v40, %0 offset:16\n\t"
        "global_load_dwordx4 v[72:75],   v40, %0 offset:32\n\t"
        "global_load_dwordx4 v[76:79],   v40, %0 offset:48\n\t"
        "global_load_dwordx4 v[80:83],   v40, %0 offset:64\n\t"
        "global_load_dwordx4 v[84:87],   v40, %0 offset:80\n\t"
        "global_load_dwordx4 v[88:91],   v40, %0 offset:96\n\t"
        "global_load_dwordx4 v[92:95],   v40, %0 offset:112\n\t"
        "global_load_dwordx4 v[96:99],   v40, %0 offset:128\n\t"
        "global_load_dwordx4 v[100:103], v40, %0 offset:144\n\t"
        "global_load_dwordx4 v[104:107], v40, %0 offset:160\n\t"
        "global_load_dwordx4 v[108:111], v40, %0 offset:176\n\t"
        "global_load_dwordx4 v[112:115], v40, %0 offset:192\n\t"
        "global_load_dwordx4 v[116:119], v40, %0 offset:208\n\t"
        "global_load_dwordx4 v[120:123], v40, %0 offset:224\n\t"
        "global_load_dwordx4 v[124:127], v40, %0 offset:240\n\t"
        "s_waitcnt vmcnt(0)\n\t"
        :: "s"(xp), "s"(op), "v"(off0)
        : "memory","s8","s11",
          "v30","v31","v33","v40","v48","v49",
          "v64","v65","v66","v67","v68","v69","v70","v71",
          "v72","v73","v74","v75","v76","v77","v78","v79",
          "v80","v81","v82","v83","v84","v85","v86","v87",
          "v88","v89","v90","v91","v92","v93","v94","v95",
          "v96","v97","v98","v99","v100","v101","v102","v103",
          "v104","v105","v106","v107","v108","v109","v110","v111",
          "v112","v113","v114","v115","v116","v117","v118","v119",
          "v120","v121","v122","v123","v124","v125","v126","v127");

    // 127 iterations x 16 chunks; slot j consumes chunk (16*it + j) and
    // prefetches chunk (16*it + j + 16). Last prefetch: it=126, j=15 ->
    // chunk 2047 (in bounds).
#pragma clang loop unroll(disable)
    for (int it = 0; it < 127; ++it) {
        SLOT( 64, 65, 66, 67, 128,129,130,131,   0, 256);
        SLOT( 68, 69, 70, 71, 132,133,134,135,  16, 272);
        SLOT( 72, 73, 74, 75, 136,137,138,139,  32, 288);
        SLOT( 76, 77, 78, 79, 140,141,142,143,  48, 304);
        SLOT( 80, 81, 82, 83, 144,145,146,147,  64, 320);
        SLOT( 84, 85, 86, 87, 148,149,150,151,  80, 336);
        SLOT( 88, 89, 90, 91, 152,153,154,155,  96, 352);
        SLOT( 92, 93, 94, 95, 156,157,158,159, 112, 368);
        SLOT( 96, 97, 98, 99, 160,161,162,163, 128, 384);
        SLOT(100,101,102,103, 164,165,166,167, 144, 400);
        SLOT(104,105,106,107, 168,169,170,171, 160, 416);
        SLOT(108,109,110,111, 172,173,174,175, 176, 432);
        SLOT(112,113,114,115, 176,177,178,179, 192, 448);
        SLOT(116,117,118,119, 180,181,182,183, 208, 464);
        SLOT(120,121,122,123, 184,185,186,187, 224, 480);
        SLOT(124,125,126,127, 188,189,190,191, 240, 496);
        asm volatile("v_add_u32 v40, 0x100, v40" ::: "v40");
    }

    // Final 16 chunks (2032..2047): drain once, then compute+store only.
    asm volatile("s_waitcnt vmcnt(0)" ::: "memory");
    SLOTND( 64, 65, 66, 67, 128,129,130,131,   0);
    SLOTND( 68, 69, 70, 71, 132,133,134,135,  16);
    SLOTND( 72, 73, 74, 75, 136,137,138,139,  32);
    SLOTND( 76, 77, 78, 79, 140,141,142,143,  48);
    SLOTND( 80, 81, 82, 83, 144,145,146,147,  64);
    SLOTND( 84, 85, 86, 87, 148,149,150,151,  80);
    SLOTND( 88, 89, 90, 91, 152,153,154,155,  96);
    SLOTND( 92, 93, 94, 95, 156,157,158,159, 112);
    SLOTND( 96, 97, 98, 99, 160,161,162,163, 128);
    SLOTND(100,101,102,103, 164,165,166,167, 144);
    SLOTND(104,105,106,107, 168,169,170,171, 160);
    SLOTND(108,109,110,111, 172,173,174,175, 176);
    SLOTND(112,113,114,115, 176,177,178,179, 192);
    SLOTND(116,117,118,119, 180,181,182,183, 208);
    SLOTND(120,121,122,123, 184,185,186,187, 224);
    SLOTND(124,125,126,127, 188,189,190,191, 240);
}

extern "C" void kernel_launch(void* const* d_in, const int* in_sizes, int n_in,
                              void* d_out, int out_size, void* d_ws, size_t ws_size,
                              hipStream_t stream) {
    const float* x   = (const float*)d_in[0];
    float*       out = (float*)d_out;
    dm_scan<<<NBLK, 64, 0, stream>>>(x, out);
}

// Round 19
// 127.655 us; speedup vs baseline: 2.7825x; 1.1776x over previous
//
#include <hip/hip_runtime.h>

// DeltaModulationEncoder: x (16, 256, 8192) f32 -> spikes {-1,0,1} f32.
// Exact monolithic scan (recurrence serial per channel).
//
// Calibrated model (fits R12-R17): wall = 8192 x ninstr x ~6.4 cyc at 1
// wave/SIMD — pure per-wave issue cadence; dependencies/ILP irrelevant
// (R16 null). Memory fully hidden by the hand-asm 16-deep pipeline (R12+).
// R18 failed on a CONSTANT bug: scale was 2^126 but bias was -0.1*2^127
// (deadband doubled -> absmax exactly 1.0). This round: same kernel, both
// exponents 126 (v30 = 2^126 = 0x7E800000, v31 = -0.1*2^126 = 0xFCCCCCCD).
//
// 5-instr step, bit-exact vs reference:
//   err   = x - r                          (identical sub)
//   t     = fma(|err|, 2^126, -th*2^126)   (= (|err|-th)*2^126 exactly in the
//           Sterbenz range [0.05,0.2]; min nonzero |t| = ulp(0.1)*2^126 =
//           2^99 >= 1; t=+0 at ==th -> strict >, like ref; |err|>0.2 ->
//           unambiguously positive, overflow -> +inf, still positive)
//   mag   = med3(t, 0, 1.0)                (exactly {0, 1.0})
//   spike = bfi(0x80000000, err, mag)      (sign(err)|mag = +-1.0f or +-0.0f;
//           -0.0f inside deadband is absmax-invisible and fma-neutral)
//   r     = fma(spike, th, r)              (spike*th exact +-0.1f/0 -> fma ==
//           ref's recon+net*th bit-identically; r never -0.0f)
// NaN impossible (finite inputs).
//
// Waits: one s_waitcnt vmcnt(24) per 4-slot group. Steady state: 32
// outstanding before the wait; the 8 retired are exactly group (g-4)'s
// store/load pairs — whose loads feed THIS group's 4 slots and whose stores
// guard this group's spike regs. Groups g-3..g-1 = 24 ops stay in flight.
//
// Register map (fixed): v33 recon | v40 voffset | v48,v49 temps |
//   v30=2^126, v31=-th*2^126 | s8=+0.1f, s10=0x80000000 |
//   v[64+4j..67+4j]   q[j] 16-deep load pipeline (j=0..15)
//   v[128+4j..131+4j] spike set j (rotating)
// 256 blocks x 1 wave; lanes 0-15 own one channel each (4096 total).

constexpr int T    = 8192;
constexpr int NCH  = 4096;
constexpr int CPB  = 16;
constexpr int NBLK = NCH / CPB;   // 256

#define STEP(X,S) \
  "v_sub_f32 v48, v" #X ", v33\n\t"            /* err = x - r          */ \
  "v_fma_f32 v49, |v48|, v30, v31\n\t"         /* t=(|err|-th)*2^126   */ \
  "v_med3_f32 v49, v49, 0, 1.0\n\t"            /* mag in {0,1}         */ \
  "v_bfi_b32 v" #S ", s10, v48, v49\n\t"       /* spike=sgn(err)|mag   */ \
  "v_fma_f32 v33, v" #S ", s8, v33\n\t"        /* r += spike*th (exact)*/

#define SLOT_CLOB(Q0,Q1,Q2,Q3,P0,P1,P2,P3) \
  "memory","s8","s10","v30","v31","v33","v48","v49", \
  "v" #Q0,"v" #Q1,"v" #Q2,"v" #Q3,"v" #P0,"v" #P1,"v" #P2,"v" #P3

// Group-leading slot: merged wait + 4 steps + store(chunk) + load(chunk+16).
#define SLOTW(Q0,Q1,Q2,Q3,P0,P1,P2,P3,OFFS,OFFL) asm volatile( \
  "s_waitcnt vmcnt(24)\n\t" \
  STEP(Q0,P0) STEP(Q1,P1) STEP(Q2,P2) STEP(Q3,P3) \
  "global_store_dwordx4 v40, v[" #P0 ":" #P3 "], %1 offset:" #OFFS "\n\t" \
  "global_load_dwordx4 v[" #Q0 ":" #Q3 "], v40, %0 offset:" #OFFL "\n\t" \
  :: "s"(xp), "s"(op) : SLOT_CLOB(Q0,Q1,Q2,Q3,P0,P1,P2,P3))

// In-group slot: no wait (covered by the group leader's vmcnt(24)).
#define SLOTN(Q0,Q1,Q2,Q3,P0,P1,P2,P3,OFFS,OFFL) asm volatile( \
  STEP(Q0,P0) STEP(Q1,P1) STEP(Q2,P2) STEP(Q3,P3) \
  "global_store_dwordx4 v40, v[" #P0 ":" #P3 "], %1 offset:" #OFFS "\n\t" \
  "global_load_dwordx4 v[" #Q0 ":" #Q3 "], v40, %0 offset:" #OFFL "\n\t" \
  :: "s"(xp), "s"(op) : SLOT_CLOB(Q0,Q1,Q2,Q3,P0,P1,P2,P3))

// Drain-phase slot: no wait, no load.
#define SLOTND(Q0,Q1,Q2,Q3,P0,P1,P2,P3,OFFS) asm volatile( \
  STEP(Q0,P0) STEP(Q1,P1) STEP(Q2,P2) STEP(Q3,P3) \
  "global_store_dwordx4 v40, v[" #P0 ":" #P3 "], %1 offset:" #OFFS "\n\t" \
  :: "s"(xp), "s"(op) : SLOT_CLOB(Q0,Q1,Q2,Q3,P0,P1,P2,P3))

__global__ __launch_bounds__(64, 1) void dm_scan(const float* __restrict__ x,
                                                 float* __restrict__ out) {
    const int lane = threadIdx.x;
    if (lane >= CPB) return;                  // exec = 0xFFFF for the rest
    const int ch = blockIdx.x * CPB + lane;

    const float* xp = x;                      // uniform -> "s" (SADDR base)
    float*       op = out;
    unsigned off0 = (unsigned)ch * (unsigned)(T * 4);   // per-lane byte offset

    // Prologue: consts, recon=0, voffset, fill the 16-slot pipeline, drain.
    asm volatile(
        "s_mov_b32 s8, 0x3dcccccd\n\t"        // +0.1f (fma operand)
        "s_mov_b32 s10, 0x80000000\n\t"       // sign-select mask for bfi
        "v_mov_b32 v30, 0x7e800000\n\t"       // 2^126
        "v_mov_b32 v31, 0xfccccccd\n\t"       // -0.1f * 2^126 (exact)
        "v_mov_b32 v33, 0\n\t"
        "v_mov_b32 v40, %2\n\t"
        "global_load_dwordx4 v[64:67],   v40, %0\n\t"
        "global_load_dwordx4 v[68:71],   v40, %0 offset:16\n\t"
        "global_load_dwordx4 v[72:75],   v40, %0 offset:32\n\t"
        "global_load_dwordx4 v[76:79],   v40, %0 offset:48\n\t"
        "global_load_dwordx4 v[80:83],   v40, %0 offset:64\n\t"
        "global_load_dwordx4 v[84:87],   v40, %0 offset:80\n\t"
        "global_load_dwordx4 v[88:91],   v40, %0 offset:96\n\t"
        "global_load_dwordx4 v[92:95],   v40, %0 offset:112\n\t"
        "global_load_dwordx4 v[96:99],   v40, %0 offset:128\n\t"
        "global_load_dwordx4 v[100:103], v40, %0 offset:144\n\t"
        "global_load_dwordx4 v[104:107], v40, %0 offset:160\n\t"
        "global_load_dwordx4 v[108:111], v40, %0 offset:176\n\t"
        "global_load_dwordx4 v[112:115], v40, %0 offset:192\n\t"
        "global_load_dwordx4 v[116:119], v40, %0 offset:208\n\t"
        "global_load_dwordx4 v[120:123], v40, %0 offset:224\n\t"
        "global_load_dwordx4 v[124:127], v40, %0 offset:240\n\t"
        "s_waitcnt vmcnt(0)\n\t"
        :: "s"(xp), "s"(op), "v"(off0)
        : "memory","s8","s10",
          "v30","v31","v33","v40","v48","v49",
          "v64","v65","v66","v67","v68","v69","v70","v71",
          "v72","v73","v74","v75","v76","v77","v78","v79",
          "v80","v81","v82","v83","v84","v85","v86","v87",
          "v88","v89","v90","v91","v92","v93","v94","v95",
          "v96","v97","v98","v99","v100","v101","v102","v103",
          "v104","v105","v106","v107","v108","v109","v110","v111",
          "v112","v113","v114","v115","v116","v117","v118","v119",
          "v120","v121","v122","v123","v124","v125","v126","v127");

    // 127 iterations x 16 slots (4 groups of 4); slot j consumes chunk
    // (16*it + j) and prefetches chunk (16*it + j + 16). Last prefetch:
    // it=126, j=15 -> chunk 2047 (in bounds).
#pragma clang loop unroll(disable)
    for (int it = 0; it < 127; ++it) {
        SLOTW( 64, 65, 66, 67, 128,129,130,131,   0, 256);
        SLOTN( 68, 69, 70, 71, 132,133,134,135,  16, 272);
        SLOTN( 72, 73, 74, 75, 136,137,138,139,  32, 288);
        SLOTN( 76, 77, 78, 79, 140,141,142,143,  48, 304);
        SLOTW( 80, 81, 82, 83, 144,145,146,147,  64, 320);
        SLOTN( 84, 85, 86, 87, 148,149,150,151,  80, 336);
        SLOTN( 88, 89, 90, 91, 152,153,154,155,  96, 352);
        SLOTN( 92, 93, 94, 95, 156,157,158,159, 112, 368);
        SLOTW( 96, 97, 98, 99, 160,161,162,163, 128, 384);
        SLOTN(100,101,102,103, 164,165,166,167, 144, 400);
        SLOTN(104,105,106,107, 168,169,170,171, 160, 416);
        SLOTN(108,109,110,111, 172,173,174,175, 176, 432);
        SLOTW(112,113,114,115, 176,177,178,179, 192, 448);
        SLOTN(116,117,118,119, 180,181,182,183, 208, 464);
        SLOTN(120,121,122,123, 184,185,186,187, 224, 480);
        SLOTN(124,125,126,127, 188,189,190,191, 240, 496);
        asm volatile("v_add_u32 v40, 0x100, v40" ::: "v40");
    }

    // Final 16 chunks (2032..2047): drain once, then compute+store only.
    asm volatile("s_waitcnt vmcnt(0)" ::: "memory");
    SLOTND( 64, 65, 66, 67, 128,129,130,131,   0);
    SLOTND( 68, 69, 70, 71, 132,133,134,135,  16);
    SLOTND( 72, 73, 74, 75, 136,137,138,139,  32);
    SLOTND( 76, 77, 78, 79, 140,141,142,143,  48);
    SLOTND( 80, 81, 82, 83, 144,145,146,147,  64);
    SLOTND( 84, 85, 86, 87, 148,149,150,151,  80);
    SLOTND( 88, 89, 90, 91, 152,153,154,155,  96);
    SLOTND( 92, 93, 94, 95, 156,157,158,159, 112);
    SLOTND( 96, 97, 98, 99, 160,161,162,163, 128);
    SLOTND(100,101,102,103, 164,165,166,167, 144);
    SLOTND(104,105,106,107, 168,169,170,171, 160);
    SLOTND(108,109,110,111, 172,173,174,175, 176);
    SLOTND(112,113,114,115, 176,177,178,179, 192);
    SLOTND(116,117,118,119, 180,181,182,183, 208);
    SLOTND(120,121,122,123, 184,185,186,187, 224);
    SLOTND(124,125,126,127, 188,189,190,191, 240);
}

extern "C" void kernel_launch(void* const* d_in, const int* in_sizes, int n_in,
                              void* d_out, int out_size, void* d_ws, size_t ws_size,
                              hipStream_t stream) {
    const float* x   = (const float*)d_in[0];
    float*       out = (float*)d_out;
    dm_scan<<<NBLK, 64, 0, stream>>>(x, out);
}